// Round 1
// baseline (479.336 us; speedup 1.0000x reference)
//
#include <hip/hip_runtime.h>

// GCN 3-layer fused pipeline for MI355X.
// Strategy: build CSR by dst on-device each call (hist -> scan -> scatter),
// then per layer: GEMM with dinv-row-scaled epilogue -> pull-mode aggregation
// (no atomics on features) with fused bias/BN/LeakyReLU epilogue.

#define LRELU_SLOPE 0.1f
#define BN_EPS 1e-5f

__global__ void zero_i32(int* __restrict__ p, int n) {
    int i = blockIdx.x * blockDim.x + threadIdx.x;
    if (i < n) p[i] = 0;
}

__global__ void hist_kernel(const int* __restrict__ dst, int* __restrict__ cnt, int E) {
    int i = blockIdx.x * blockDim.x + threadIdx.x;
    if (i < E) atomicAdd(&cnt[dst[i]], 1);
}

__global__ void dinv_kernel(const int* __restrict__ cnt, float* __restrict__ dinv, int n) {
    int i = blockIdx.x * blockDim.x + threadIdx.x;
    if (i < n) dinv[i] = rsqrtf(1.0f + (float)cnt[i]);
}

// Block-level inclusive scan (256 elements per block) + per-block totals.
__global__ void scan1(const int* __restrict__ cnt, int* __restrict__ incl,
                      int* __restrict__ part, int n) {
    __shared__ int s[256];
    int tid = threadIdx.x;
    int gid = blockIdx.x * 256 + tid;
    int v = (gid < n) ? cnt[gid] : 0;
    s[tid] = v;
    __syncthreads();
    for (int off = 1; off < 256; off <<= 1) {
        int t = (tid >= off) ? s[tid - off] : 0;
        __syncthreads();
        s[tid] += t;
        __syncthreads();
    }
    if (gid < n) incl[gid] = s[tid];
    if (tid == 255) part[blockIdx.x] = s[255];
}

// Exclusive scan of per-block totals (single block; nb <= 256).
__global__ void scan2(const int* __restrict__ part, int* __restrict__ poff, int nb) {
    __shared__ int s[256];
    int tid = threadIdx.x;
    int v = (tid < nb) ? part[tid] : 0;
    s[tid] = v;
    __syncthreads();
    for (int off = 1; off < 256; off <<= 1) {
        int t = (tid >= off) ? s[tid - off] : 0;
        __syncthreads();
        s[tid] += t;
        __syncthreads();
    }
    poff[tid] = s[tid] - v;  // exclusive
}

__global__ void scan3(const int* __restrict__ cnt, const int* __restrict__ incl,
                      const int* __restrict__ poff, int* __restrict__ row_ptr,
                      int* __restrict__ cursor, int n, int E) {
    int gid = blockIdx.x * 256 + threadIdx.x;
    if (gid < n) {
        int rp = incl[gid] - cnt[gid] + poff[blockIdx.x];
        row_ptr[gid] = rp;
        cursor[gid] = rp;
    }
    if (gid == 0) row_ptr[n] = E;
}

__global__ void scatter_kernel(const int* __restrict__ src, const int* __restrict__ dst,
                               int* __restrict__ cursor, int* __restrict__ ssrc, int E) {
    int i = blockIdx.x * blockDim.x + threadIdx.x;
    if (i < E) {
        int d = dst[i];
        int pos = atomicAdd(&cursor[d], 1);
        ssrc[pos] = src[i];
    }
}

// H[r][c] = (sum_k X[r][k] * W[k][c]) * dinv[r]
// K fixed at 128. Block computes 64 rows x NC cols; X tile staged in LDS
// (padded stride 132 -> conflict-free b32 reads), W streamed from L1/L2.
template <int NC>
__global__ __launch_bounds__(256) void gemm_scaled(const float* __restrict__ X,
                                                   const float* __restrict__ W,
                                                   const float* __restrict__ dinv,
                                                   float* __restrict__ H, int nrows) {
    constexpr int CT = NC / 8;    // col-threads (16 or 8)
    constexpr int RT = 256 / CT;  // row-threads (16 or 32)
    constexpr int RPT = 64 / RT;  // rows per thread (4 or 2)
    __shared__ float Xl[64][132];

    const int tid = threadIdx.x;
    const int row0 = blockIdx.x * 64;

    // Stage X tile: 64 rows x 128 cols = 2048 float4 granules.
    for (int i = tid; i < 2048; i += 256) {
        int rr = i >> 5;
        int cc = (i & 31) << 2;
        int gr = row0 + rr;
        if (gr > nrows - 1) gr = nrows - 1;
        const float4 xv = *reinterpret_cast<const float4*>(&X[(size_t)gr * 128 + cc]);
        *reinterpret_cast<float4*>(&Xl[rr][cc]) = xv;
    }
    __syncthreads();

    const int ct = tid % CT;
    const int rt = tid / CT;
    const int c0 = ct * 8;

    float acc[RPT][8];
#pragma unroll
    for (int i = 0; i < RPT; ++i)
#pragma unroll
        for (int j = 0; j < 8; ++j) acc[i][j] = 0.f;

#pragma unroll 4
    for (int k = 0; k < 128; ++k) {
        const float4 w0 = *reinterpret_cast<const float4*>(&W[k * NC + c0]);
        const float4 w1 = *reinterpret_cast<const float4*>(&W[k * NC + c0 + 4]);
#pragma unroll
        for (int i = 0; i < RPT; ++i) {
            const float xv = Xl[i * RT + rt][k];
            acc[i][0] = fmaf(xv, w0.x, acc[i][0]);
            acc[i][1] = fmaf(xv, w0.y, acc[i][1]);
            acc[i][2] = fmaf(xv, w0.z, acc[i][2]);
            acc[i][3] = fmaf(xv, w0.w, acc[i][3]);
            acc[i][4] = fmaf(xv, w1.x, acc[i][4]);
            acc[i][5] = fmaf(xv, w1.y, acc[i][5]);
            acc[i][6] = fmaf(xv, w1.z, acc[i][6]);
            acc[i][7] = fmaf(xv, w1.w, acc[i][7]);
        }
    }

#pragma unroll
    for (int i = 0; i < RPT; ++i) {
        const int r = row0 + i * RT + rt;
        if (r < nrows) {
            const float s = dinv[r];
            float4 o0, o1;
            o0.x = acc[i][0] * s; o0.y = acc[i][1] * s;
            o0.z = acc[i][2] * s; o0.w = acc[i][3] * s;
            o1.x = acc[i][4] * s; o1.y = acc[i][5] * s;
            o1.z = acc[i][6] * s; o1.w = acc[i][7] * s;
            *reinterpret_cast<float4*>(&H[(size_t)r * NC + c0]) = o0;
            *reinterpret_cast<float4*>(&H[(size_t)r * NC + c0 + 4]) = o1;
        }
    }
}

// out[n][f] = epilogue( dinv[n] * (H[n][f] + sum_{e in CSR row n} H[ssrc[e]][f]) + b[f] )
// One NC-thread group per node; edge-loop bounds are wave-uniform.
template <int NC, bool BN>
__global__ __launch_bounds__(256) void agg_kernel(
    const float* __restrict__ H, const int* __restrict__ row_ptr,
    const int* __restrict__ ssrc, const float* __restrict__ dinv,
    const float* __restrict__ b, const float* __restrict__ g,
    const float* __restrict__ be, const float* __restrict__ m,
    const float* __restrict__ v, float* __restrict__ out, int n) {
    constexpr int NPB = 256 / NC;  // nodes per block
    const int tid = threadIdx.x;
    const int node = blockIdx.x * NPB + tid / NC;
    const int f = tid % NC;
    if (node >= n) return;

    const int e0 = row_ptr[node];
    const int e1 = row_ptr[node + 1];

    float a0 = H[(size_t)node * NC + f];  // self-loop term (already dinv-scaled)
    float a1 = 0.f, a2 = 0.f, a3 = 0.f;
    int e = e0;
    for (; e + 3 < e1; e += 4) {
        const int sA = ssrc[e], sB = ssrc[e + 1], sC = ssrc[e + 2], sD = ssrc[e + 3];
        a0 += H[(size_t)sA * NC + f];
        a1 += H[(size_t)sB * NC + f];
        a2 += H[(size_t)sC * NC + f];
        a3 += H[(size_t)sD * NC + f];
    }
    for (; e < e1; ++e) a1 += H[(size_t)ssrc[e] * NC + f];

    const float acc = (a0 + a1) + (a2 + a3);
    float val = acc * dinv[node] + b[f];
    if constexpr (BN) {
        val = (val - m[f]) * rsqrtf(v[f] + BN_EPS) * g[f] + be[f];
        val = val > 0.f ? val : LRELU_SLOPE * val;
    }
    out[(size_t)node * NC + f] = val;
}

extern "C" void kernel_launch(void* const* d_in, const int* in_sizes, int n_in,
                              void* d_out, int out_size, void* d_ws, size_t ws_size,
                              hipStream_t stream) {
    const float* x  = (const float*)d_in[0];
    const int* ei   = (const int*)d_in[1];
    const float* W1 = (const float*)d_in[2];
    const float* b1 = (const float*)d_in[3];
    const float* g1 = (const float*)d_in[4];
    const float* be1= (const float*)d_in[5];
    const float* m1 = (const float*)d_in[6];
    const float* v1 = (const float*)d_in[7];
    const float* W2 = (const float*)d_in[8];
    const float* b2 = (const float*)d_in[9];
    const float* g2 = (const float*)d_in[10];
    const float* be2= (const float*)d_in[11];
    const float* m2 = (const float*)d_in[12];
    const float* v2 = (const float*)d_in[13];
    const float* W3 = (const float*)d_in[14];
    const float* b3 = (const float*)d_in[15];
    float* out = (float*)d_out;

    const int N = in_sizes[0] / 128;
    const int E = in_sizes[1] / 2;
    const int* srcIdx = ei;       // edge_index[0]
    const int* dstIdx = ei + E;   // edge_index[1]

    // Workspace carve (needs ~56 MB).
    char* p = (char*)d_ws;
    auto carve = [&](size_t bytes) -> void* {
        void* r = (void*)p;
        p += (bytes + 255) & ~(size_t)255;
        return r;
    };
    int* cnt     = (int*)carve((size_t)N * 4);
    int* incl    = (int*)carve((size_t)N * 4);
    int* part    = (int*)carve(1024);
    int* poff    = (int*)carve(1024);
    int* row_ptr = (int*)carve((size_t)(N + 1) * 4);
    int* cursor  = (int*)carve((size_t)N * 4);
    float* dinv  = (float*)carve((size_t)N * 4);
    int* ssrc    = (int*)carve((size_t)E * 4);
    float* Hb    = (float*)carve((size_t)N * 128 * 4);
    float* Xb    = (float*)carve((size_t)N * 128 * 4);
    (void)ws_size; (void)n_in; (void)out_size;

    const int nb_n = (N + 255) / 256;  // 196 (fits single-block scan2)
    const int nb_e = (E + 255) / 256;

    // Degree + CSR build.
    zero_i32<<<nb_n, 256, 0, stream>>>(cnt, N);
    hist_kernel<<<nb_e, 256, 0, stream>>>(dstIdx, cnt, E);
    dinv_kernel<<<nb_n, 256, 0, stream>>>(cnt, dinv, N);
    scan1<<<nb_n, 256, 0, stream>>>(cnt, incl, part, N);
    scan2<<<1, 256, 0, stream>>>(part, poff, nb_n);
    scan3<<<nb_n, 256, 0, stream>>>(cnt, incl, poff, row_ptr, cursor, N, E);
    scatter_kernel<<<nb_e, 256, 0, stream>>>(srcIdx, dstIdx, cursor, ssrc, E);

    const int gb = (N + 63) / 64;

    // Layer 1: x -> Xb
    gemm_scaled<128><<<gb, 256, 0, stream>>>(x, W1, dinv, Hb, N);
    agg_kernel<128, true><<<(N + 1) / 2, 256, 0, stream>>>(
        Hb, row_ptr, ssrc, dinv, b1, g1, be1, m1, v1, Xb, N);

    // Layer 2: Xb -> Xb (via Hb)
    gemm_scaled<128><<<gb, 256, 0, stream>>>(Xb, W2, dinv, Hb, N);
    agg_kernel<128, true><<<(N + 1) / 2, 256, 0, stream>>>(
        Hb, row_ptr, ssrc, dinv, b2, g2, be2, m2, v2, Xb, N);

    // Layer 3: Xb -> out (64 cols, no BN/activation)
    gemm_scaled<64><<<gb, 256, 0, stream>>>(Xb, W3, dinv, Hb, N);
    agg_kernel<64, false><<<(N + 3) / 4, 256, 0, stream>>>(
        Hb, row_ptr, ssrc, dinv, b3, nullptr, nullptr, nullptr, nullptr, out, N);
}

// Round 2
// 390.791 us; speedup vs baseline: 1.2266x; 1.2266x over previous
//
#include <hip/hip_runtime.h>
#include <hip/hip_fp16.h>

// GCN 3-layer fused pipeline for MI355X.
// CSR build by dst (hist -> scan -> scatter), then per layer:
// f32 GEMM with dinv-row-scale epilogue storing fp16 H -> pull-mode
// aggregation over fp16 H (halved gather traffic) with fused bias/BN/LeakyReLU.

#define LRELU_SLOPE 0.1f
#define BN_EPS 1e-5f

__global__ void zero_i32(int* __restrict__ p, int n) {
    int i = blockIdx.x * blockDim.x + threadIdx.x;
    if (i < n) p[i] = 0;
}

__global__ void hist_kernel(const int* __restrict__ dst, int* __restrict__ cnt, int E) {
    int i = blockIdx.x * blockDim.x + threadIdx.x;
    if (i < E) atomicAdd(&cnt[dst[i]], 1);
}

// Block-level inclusive scan (256 elements per block) + per-block totals.
__global__ void scan1(const int* __restrict__ cnt, int* __restrict__ incl,
                      int* __restrict__ part, int n) {
    __shared__ int s[256];
    int tid = threadIdx.x;
    int gid = blockIdx.x * 256 + tid;
    int v = (gid < n) ? cnt[gid] : 0;
    s[tid] = v;
    __syncthreads();
    for (int off = 1; off < 256; off <<= 1) {
        int t = (tid >= off) ? s[tid - off] : 0;
        __syncthreads();
        s[tid] += t;
        __syncthreads();
    }
    if (gid < n) incl[gid] = s[tid];
    if (tid == 255) part[blockIdx.x] = s[255];
}

// Exclusive scan of per-block totals (single block; nb <= 256).
__global__ void scan2(const int* __restrict__ part, int* __restrict__ poff, int nb) {
    __shared__ int s[256];
    int tid = threadIdx.x;
    int v = (tid < nb) ? part[tid] : 0;
    s[tid] = v;
    __syncthreads();
    for (int off = 1; off < 256; off <<= 1) {
        int t = (tid >= off) ? s[tid - off] : 0;
        __syncthreads();
        s[tid] += t;
        __syncthreads();
    }
    poff[tid] = s[tid] - v;  // exclusive
}

// row_ptr/cursor + dinv fused.
__global__ void scan3(const int* __restrict__ cnt, const int* __restrict__ incl,
                      const int* __restrict__ poff, int* __restrict__ row_ptr,
                      int* __restrict__ cursor, float* __restrict__ dinv, int n, int E) {
    int gid = blockIdx.x * 256 + threadIdx.x;
    if (gid < n) {
        int c = cnt[gid];
        int rp = incl[gid] - c + poff[blockIdx.x];
        row_ptr[gid] = rp;
        cursor[gid] = rp;
        dinv[gid] = rsqrtf(1.0f + (float)c);
    }
    if (gid == 0) row_ptr[n] = E;
}

__global__ void scatter_kernel(const int* __restrict__ src, const int* __restrict__ dst,
                               int* __restrict__ cursor, int* __restrict__ ssrc, int E) {
    int i = blockIdx.x * blockDim.x + threadIdx.x;
    if (i < E) {
        int d = dst[i];
        int pos = atomicAdd(&cursor[d], 1);
        ssrc[pos] = src[i];
    }
}

// H[r][c] = fp16( (sum_k X[r][k] * W[k][c]) * dinv[r] ),  K fixed at 128.
template <int NC>
__global__ __launch_bounds__(256) void gemm_scaled(const float* __restrict__ X,
                                                   const float* __restrict__ W,
                                                   const float* __restrict__ dinv,
                                                   __half* __restrict__ H, int nrows) {
    constexpr int CT = NC / 8;    // col-threads (16 or 8)
    constexpr int RT = 256 / CT;  // row-threads (16 or 32)
    constexpr int RPT = 64 / RT;  // rows per thread (4 or 2)
    __shared__ float Xl[64][132];

    const int tid = threadIdx.x;
    const int row0 = blockIdx.x * 64;

    // Stage X tile: 64 rows x 128 cols.
    for (int i = tid; i < 2048; i += 256) {
        int rr = i >> 5;
        int cc = (i & 31) << 2;
        int gr = row0 + rr;
        if (gr > nrows - 1) gr = nrows - 1;
        const float4 xv = *reinterpret_cast<const float4*>(&X[(size_t)gr * 128 + cc]);
        *reinterpret_cast<float4*>(&Xl[rr][cc]) = xv;
    }
    __syncthreads();

    const int ct = tid % CT;
    const int rt = tid / CT;
    const int c0 = ct * 8;

    float acc[RPT][8];
#pragma unroll
    for (int i = 0; i < RPT; ++i)
#pragma unroll
        for (int j = 0; j < 8; ++j) acc[i][j] = 0.f;

#pragma unroll 4
    for (int k = 0; k < 128; ++k) {
        const float4 w0 = *reinterpret_cast<const float4*>(&W[k * NC + c0]);
        const float4 w1 = *reinterpret_cast<const float4*>(&W[k * NC + c0 + 4]);
#pragma unroll
        for (int i = 0; i < RPT; ++i) {
            const float xv = Xl[i * RT + rt][k];
            acc[i][0] = fmaf(xv, w0.x, acc[i][0]);
            acc[i][1] = fmaf(xv, w0.y, acc[i][1]);
            acc[i][2] = fmaf(xv, w0.z, acc[i][2]);
            acc[i][3] = fmaf(xv, w0.w, acc[i][3]);
            acc[i][4] = fmaf(xv, w1.x, acc[i][4]);
            acc[i][5] = fmaf(xv, w1.y, acc[i][5]);
            acc[i][6] = fmaf(xv, w1.z, acc[i][6]);
            acc[i][7] = fmaf(xv, w1.w, acc[i][7]);
        }
    }

#pragma unroll
    for (int i = 0; i < RPT; ++i) {
        const int r = row0 + i * RT + rt;
        if (r < nrows) {
            const float s = dinv[r];
            union { __half2 h2; unsigned u; } c0u, c1u, c2u, c3u;
            c0u.h2 = __floats2half2_rn(acc[i][0] * s, acc[i][1] * s);
            c1u.h2 = __floats2half2_rn(acc[i][2] * s, acc[i][3] * s);
            c2u.h2 = __floats2half2_rn(acc[i][4] * s, acc[i][5] * s);
            c3u.h2 = __floats2half2_rn(acc[i][6] * s, acc[i][7] * s);
            uint4 o;
            o.x = c0u.u; o.y = c1u.u; o.z = c2u.u; o.w = c3u.u;
            *reinterpret_cast<uint4*>(&H[(size_t)r * NC + c0]) = o;  // 16B aligned
        }
    }
}

__device__ __forceinline__ float2 u2f2(unsigned u) {
    __half2 h;
    *reinterpret_cast<unsigned*>(&h) = u;
    return __half22float2(h);
}

// out[n][f] = epilogue( dinv[n]*(H[n][f] + sum_{e in row n} H[ssrc[e]][f]) + b[f] )
// 32 threads per node, FPT = NC/32 features per thread, 8 nodes per block.
template <int NC, bool BN>
__global__ __launch_bounds__(256) void agg_h(
    const __half* __restrict__ H, const int* __restrict__ row_ptr,
    const int* __restrict__ ssrc, const float* __restrict__ dinv,
    const float* __restrict__ b, const float* __restrict__ g,
    const float* __restrict__ be, const float* __restrict__ m,
    const float* __restrict__ v, float* __restrict__ out, int n) {
    constexpr int FPT = NC / 32;
    const int tid = threadIdx.x;
    const int node = blockIdx.x * 8 + (tid >> 5);
    const int lane = tid & 31;
    const int f0 = lane * FPT;
    if (node >= n) return;

    const int e0 = row_ptr[node];
    const int e1 = row_ptr[node + 1];

    if constexpr (FPT == 4) {
        uint2 su = *reinterpret_cast<const uint2*>(&H[(size_t)node * NC + f0]);
        float2 slo = u2f2(su.x), shi = u2f2(su.y);
        float4 A0 = {slo.x, slo.y, shi.x, shi.y};
        float4 A1 = {0, 0, 0, 0}, A2 = {0, 0, 0, 0}, A3 = {0, 0, 0, 0};
        int e = e0;
        for (; e + 3 < e1; e += 4) {
            const int sA = ssrc[e], sB = ssrc[e + 1], sC = ssrc[e + 2], sD = ssrc[e + 3];
            const uint2 uA = *reinterpret_cast<const uint2*>(&H[(size_t)sA * NC + f0]);
            const uint2 uB = *reinterpret_cast<const uint2*>(&H[(size_t)sB * NC + f0]);
            const uint2 uC = *reinterpret_cast<const uint2*>(&H[(size_t)sC * NC + f0]);
            const uint2 uD = *reinterpret_cast<const uint2*>(&H[(size_t)sD * NC + f0]);
            float2 l, h;
            l = u2f2(uA.x); h = u2f2(uA.y);
            A0.x += l.x; A0.y += l.y; A0.z += h.x; A0.w += h.y;
            l = u2f2(uB.x); h = u2f2(uB.y);
            A1.x += l.x; A1.y += l.y; A1.z += h.x; A1.w += h.y;
            l = u2f2(uC.x); h = u2f2(uC.y);
            A2.x += l.x; A2.y += l.y; A2.z += h.x; A2.w += h.y;
            l = u2f2(uD.x); h = u2f2(uD.y);
            A3.x += l.x; A3.y += l.y; A3.z += h.x; A3.w += h.y;
        }
        for (; e < e1; ++e) {
            const uint2 u = *reinterpret_cast<const uint2*>(&H[(size_t)ssrc[e] * NC + f0]);
            float2 l = u2f2(u.x), h = u2f2(u.y);
            A1.x += l.x; A1.y += l.y; A1.z += h.x; A1.w += h.y;
        }
        float4 acc;
        acc.x = (A0.x + A1.x) + (A2.x + A3.x);
        acc.y = (A0.y + A1.y) + (A2.y + A3.y);
        acc.z = (A0.z + A1.z) + (A2.z + A3.z);
        acc.w = (A0.w + A1.w) + (A2.w + A3.w);
        const float dn = dinv[node];
        float o[4] = {acc.x * dn + b[f0], acc.y * dn + b[f0 + 1],
                      acc.z * dn + b[f0 + 2], acc.w * dn + b[f0 + 3]};
        if constexpr (BN) {
#pragma unroll
            for (int j = 0; j < 4; ++j) {
                float val = (o[j] - m[f0 + j]) * rsqrtf(v[f0 + j] + BN_EPS) * g[f0 + j] + be[f0 + j];
                o[j] = val > 0.f ? val : LRELU_SLOPE * val;
            }
        }
        float4 ov = {o[0], o[1], o[2], o[3]};
        *reinterpret_cast<float4*>(&out[(size_t)node * NC + f0]) = ov;
    } else {
        unsigned su = *reinterpret_cast<const unsigned*>(&H[(size_t)node * NC + f0]);
        float2 A0 = u2f2(su);
        float2 A1 = {0, 0}, A2 = {0, 0}, A3 = {0, 0};
        int e = e0;
        for (; e + 3 < e1; e += 4) {
            const int sA = ssrc[e], sB = ssrc[e + 1], sC = ssrc[e + 2], sD = ssrc[e + 3];
            const unsigned uA = *reinterpret_cast<const unsigned*>(&H[(size_t)sA * NC + f0]);
            const unsigned uB = *reinterpret_cast<const unsigned*>(&H[(size_t)sB * NC + f0]);
            const unsigned uC = *reinterpret_cast<const unsigned*>(&H[(size_t)sC * NC + f0]);
            const unsigned uD = *reinterpret_cast<const unsigned*>(&H[(size_t)sD * NC + f0]);
            float2 f;
            f = u2f2(uA); A0.x += f.x; A0.y += f.y;
            f = u2f2(uB); A1.x += f.x; A1.y += f.y;
            f = u2f2(uC); A2.x += f.x; A2.y += f.y;
            f = u2f2(uD); A3.x += f.x; A3.y += f.y;
        }
        for (; e < e1; ++e) {
            float2 f = u2f2(*reinterpret_cast<const unsigned*>(&H[(size_t)ssrc[e] * NC + f0]));
            A1.x += f.x; A1.y += f.y;
        }
        float2 acc;
        acc.x = (A0.x + A1.x) + (A2.x + A3.x);
        acc.y = (A0.y + A1.y) + (A2.y + A3.y);
        const float dn = dinv[node];
        float o0 = acc.x * dn + b[f0];
        float o1 = acc.y * dn + b[f0 + 1];
        if constexpr (BN) {
            o0 = (o0 - m[f0]) * rsqrtf(v[f0] + BN_EPS) * g[f0] + be[f0];
            o0 = o0 > 0.f ? o0 : LRELU_SLOPE * o0;
            o1 = (o1 - m[f0 + 1]) * rsqrtf(v[f0 + 1] + BN_EPS) * g[f0 + 1] + be[f0 + 1];
            o1 = o1 > 0.f ? o1 : LRELU_SLOPE * o1;
        }
        float2 ov = {o0, o1};
        *reinterpret_cast<float2*>(&out[(size_t)node * NC + f0]) = ov;
    }
}

extern "C" void kernel_launch(void* const* d_in, const int* in_sizes, int n_in,
                              void* d_out, int out_size, void* d_ws, size_t ws_size,
                              hipStream_t stream) {
    const float* x  = (const float*)d_in[0];
    const int* ei   = (const int*)d_in[1];
    const float* W1 = (const float*)d_in[2];
    const float* b1 = (const float*)d_in[3];
    const float* g1 = (const float*)d_in[4];
    const float* be1= (const float*)d_in[5];
    const float* m1 = (const float*)d_in[6];
    const float* v1 = (const float*)d_in[7];
    const float* W2 = (const float*)d_in[8];
    const float* b2 = (const float*)d_in[9];
    const float* g2 = (const float*)d_in[10];
    const float* be2= (const float*)d_in[11];
    const float* m2 = (const float*)d_in[12];
    const float* v2 = (const float*)d_in[13];
    const float* W3 = (const float*)d_in[14];
    const float* b3 = (const float*)d_in[15];
    float* out = (float*)d_out;

    const int N = in_sizes[0] / 128;
    const int E = in_sizes[1] / 2;
    const int* srcIdx = ei;       // edge_index[0]
    const int* dstIdx = ei + E;   // edge_index[1]

    char* p = (char*)d_ws;
    auto carve = [&](size_t bytes) -> void* {
        void* r = (void*)p;
        p += (bytes + 255) & ~(size_t)255;
        return r;
    };
    int* cnt     = (int*)carve((size_t)N * 4);
    int* incl    = (int*)carve((size_t)N * 4);
    int* part    = (int*)carve(1024);
    int* poff    = (int*)carve(1024);
    int* row_ptr = (int*)carve((size_t)(N + 1) * 4);
    int* cursor  = (int*)carve((size_t)N * 4);
    float* dinv  = (float*)carve((size_t)N * 4);
    int* ssrc    = (int*)carve((size_t)E * 4);
    __half* Hb   = (__half*)carve((size_t)N * 128 * 2);
    float* Xb    = (float*)carve((size_t)N * 128 * 4);
    (void)ws_size; (void)n_in; (void)out_size;

    const int nb_n = (N + 255) / 256;  // 196 (fits single-block scan2)
    const int nb_e = (E + 255) / 256;

    zero_i32<<<nb_n, 256, 0, stream>>>(cnt, N);
    hist_kernel<<<nb_e, 256, 0, stream>>>(dstIdx, cnt, E);
    scan1<<<nb_n, 256, 0, stream>>>(cnt, incl, part, N);
    scan2<<<1, 256, 0, stream>>>(part, poff, nb_n);
    scan3<<<nb_n, 256, 0, stream>>>(cnt, incl, poff, row_ptr, cursor, dinv, N, E);
    scatter_kernel<<<nb_e, 256, 0, stream>>>(srcIdx, dstIdx, cursor, ssrc, E);

    const int gb = (N + 63) / 64;
    const int ab = (N + 7) / 8;

    // Layer 1: x -> Xb
    gemm_scaled<128><<<gb, 256, 0, stream>>>(x, W1, dinv, Hb, N);
    agg_h<128, true><<<ab, 256, 0, stream>>>(
        Hb, row_ptr, ssrc, dinv, b1, g1, be1, m1, v1, Xb, N);

    // Layer 2: Xb -> Xb (via Hb)
    gemm_scaled<128><<<gb, 256, 0, stream>>>(Xb, W2, dinv, Hb, N);
    agg_h<128, true><<<ab, 256, 0, stream>>>(
        Hb, row_ptr, ssrc, dinv, b2, g2, be2, m2, v2, Xb, N);

    // Layer 3: Xb -> out (64 cols, no BN/activation)
    gemm_scaled<64><<<gb, 256, 0, stream>>>(Xb, W3, dinv, Hb, N);
    agg_h<64, false><<<ab, 256, 0, stream>>>(
        Hb, row_ptr, ssrc, dinv, b3, nullptr, nullptr, nullptr, nullptr, out, N);
}

// Round 4
// 310.817 us; speedup vs baseline: 1.5422x; 1.2573x over previous
//
#include <hip/hip_runtime.h>
#include <hip/hip_fp16.h>

// GCN 3-layer fused pipeline for MI355X.
// CSR build by dst (hist -> scan -> scatter), then per layer:
// fp16 MFMA GEMM (W pre-transposed to LDS, dinv-scaled fp16 H epilogue) ->
// pull-mode aggregation over fp16 H with fused bias/BN/LeakyReLU epilogue.

#define LRELU_SLOPE 0.1f
#define BN_EPS 1e-5f

typedef _Float16 half8 __attribute__((ext_vector_type(8)));
typedef float f32x4 __attribute__((ext_vector_type(4)));

__global__ void zero_i32(int* __restrict__ p, int n) {
    int i = blockIdx.x * blockDim.x + threadIdx.x;
    if (i < n) p[i] = 0;
}

__global__ void hist_kernel(const int* __restrict__ dst, int* __restrict__ cnt, int E) {
    int i = blockIdx.x * blockDim.x + threadIdx.x;
    if (i < E) atomicAdd(&cnt[dst[i]], 1);
}

// Convert + transpose all three W matrices to padded fp16 Wt[c][k] (stride 136).
__global__ void prep_w(const float* __restrict__ W1, const float* __restrict__ W2,
                       const float* __restrict__ W3, _Float16* __restrict__ W1t,
                       _Float16* __restrict__ W2t, _Float16* __restrict__ W3t) {
    int i = blockIdx.x * 256 + threadIdx.x;
    if (i < 16384) {
        int k = i >> 7, c = i & 127;
        W1t[c * 136 + k] = (_Float16)W1[i];
    } else if (i < 32768) {
        int j = i - 16384;
        int k = j >> 7, c = j & 127;
        W2t[c * 136 + k] = (_Float16)W2[j];
    } else if (i < 40960) {
        int j = i - 32768;
        int k = j >> 6, c = j & 63;
        W3t[c * 136 + k] = (_Float16)W3[j];
    }
}

// Block-level inclusive scan (256 elements per block) + per-block totals.
__global__ void scan1(const int* __restrict__ cnt, int* __restrict__ incl,
                      int* __restrict__ part, int n) {
    __shared__ int s[256];
    int tid = threadIdx.x;
    int gid = blockIdx.x * 256 + tid;
    int v = (gid < n) ? cnt[gid] : 0;
    s[tid] = v;
    __syncthreads();
    for (int off = 1; off < 256; off <<= 1) {
        int t = (tid >= off) ? s[tid - off] : 0;
        __syncthreads();
        s[tid] += t;
        __syncthreads();
    }
    if (gid < n) incl[gid] = s[tid];
    if (tid == 255) part[blockIdx.x] = s[255];
}

__global__ void scan2(const int* __restrict__ part, int* __restrict__ poff, int nb) {
    __shared__ int s[256];
    int tid = threadIdx.x;
    int v = (tid < nb) ? part[tid] : 0;
    s[tid] = v;
    __syncthreads();
    for (int off = 1; off < 256; off <<= 1) {
        int t = (tid >= off) ? s[tid - off] : 0;
        __syncthreads();
        s[tid] += t;
        __syncthreads();
    }
    poff[tid] = s[tid] - v;  // exclusive
}

__global__ void scan3(const int* __restrict__ cnt, const int* __restrict__ incl,
                      const int* __restrict__ poff, int* __restrict__ row_ptr,
                      int* __restrict__ cursor, float* __restrict__ dinv, int n, int E) {
    int gid = blockIdx.x * 256 + threadIdx.x;
    if (gid < n) {
        int c = cnt[gid];
        int rp = incl[gid] - c + poff[blockIdx.x];
        row_ptr[gid] = rp;
        cursor[gid] = rp;
        dinv[gid] = rsqrtf(1.0f + (float)c);
    }
    if (gid == 0) row_ptr[n] = E;
}

__global__ void scatter_kernel(const int* __restrict__ src, const int* __restrict__ dst,
                               int* __restrict__ cursor, int* __restrict__ ssrc, int E) {
    int i = blockIdx.x * blockDim.x + threadIdx.x;
    if (i < E) {
        int d = dst[i];
        int pos = atomicAdd(&cursor[d], 1);
        ssrc[pos] = src[i];
    }
}

// H[r][c] = fp16( (sum_k A[r][k] * W[k][c]) * dinv[r] ),  K fixed at 128.
// MFMA f32_16x16x32_f16. Block: 256 thr = 4 waves, tile M=64 x N=NC.
// Wt (padded [NC][136] fp16) staged in LDS; A-frags loaded from global;
// C transposed through LDS for coalesced fp16 stores.
template <int NC, bool AF32>
__global__ __launch_bounds__(256) void gemm_mfma(const void* __restrict__ Ain,
                                                 const _Float16* __restrict__ Wt,
                                                 const float* __restrict__ dinv,
                                                 __half* __restrict__ H, int nrows) {
    constexpr int NT = NC / 16;                    // N fragments per wave
    constexpr int SPH = (NC == 128) ? 136 : 88;    // Hl padded row (halves)
    __shared__ _Float16 smem[NC * 136];

    const int tid = threadIdx.x;
    const int row0 = blockIdx.x * 64;

    // Stage Wt into LDS (uint4 granules; pad bytes copied but never read).
    {
        const uint4* src = reinterpret_cast<const uint4*>(Wt);
        uint4* dst = reinterpret_cast<uint4*>(smem);
        for (int i = tid; i < NC * 17; i += 256) dst[i] = src[i];
    }
    __syncthreads();

    const int w = tid >> 6;
    const int lane = tid & 63;
    const int l15 = lane & 15;
    const int kg = lane >> 4;  // 0..3

    // A fragments: row = l15 (within wave tile), k = ks*32 + kg*8 .. +7
    int ar = row0 + w * 16 + l15;
    if (ar > nrows - 1) ar = nrows - 1;
    half8 a[4];
#pragma unroll
    for (int ks = 0; ks < 4; ++ks) {
        const int cb = ks * 32 + kg * 8;
        if constexpr (AF32) {
            const float* Xf = (const float*)Ain;
            const float4 x0 = *reinterpret_cast<const float4*>(&Xf[(size_t)ar * 128 + cb]);
            const float4 x1 = *reinterpret_cast<const float4*>(&Xf[(size_t)ar * 128 + cb + 4]);
            half8 av;
            av[0] = (_Float16)x0.x; av[1] = (_Float16)x0.y;
            av[2] = (_Float16)x0.z; av[3] = (_Float16)x0.w;
            av[4] = (_Float16)x1.x; av[5] = (_Float16)x1.y;
            av[6] = (_Float16)x1.z; av[7] = (_Float16)x1.w;
            a[ks] = av;
        } else {
            const __half* Xh = (const __half*)Ain;
            a[ks] = *reinterpret_cast<const half8*>(&Xh[(size_t)ar * 128 + cb]);
        }
    }

    f32x4 acc[NT];
#pragma unroll
    for (int nt = 0; nt < NT; ++nt) acc[nt] = {0.f, 0.f, 0.f, 0.f};

#pragma unroll
    for (int nt = 0; nt < NT; ++nt) {
        const int c = nt * 16 + l15;
#pragma unroll
        for (int ks = 0; ks < 4; ++ks) {
            const half8 b = *reinterpret_cast<const half8*>(&smem[c * 136 + ks * 32 + kg * 8]);
            acc[nt] = __builtin_amdgcn_mfma_f32_16x16x32_f16(a[ks], b, acc[nt], 0, 0, 0);
        }
    }

    __syncthreads();  // all B-reads done; reuse smem as Hl[64][SPH]

    // C layout: col = l15 (+nt*16), row = kg*4 + reg (within wave tile).
    float dv[4];
#pragma unroll
    for (int r = 0; r < 4; ++r) {
        int gr = row0 + w * 16 + kg * 4 + r;
        if (gr > nrows - 1) gr = nrows - 1;
        dv[r] = dinv[gr];
    }
    _Float16* Hl = smem;
#pragma unroll
    for (int nt = 0; nt < NT; ++nt) {
#pragma unroll
        for (int r = 0; r < 4; ++r) {
            Hl[(w * 16 + kg * 4 + r) * SPH + nt * 16 + l15] = (_Float16)(acc[nt][r] * dv[r]);
        }
    }
    __syncthreads();

    // Coalesced store: 64 rows x NC halves, uint4 (8 halves) per thread-iter.
    constexpr int CG = NC / 8;
    for (int i = tid; i < 64 * CG; i += 256) {
        const int row = i / CG, cg = i % CG;
        const int gr = row0 + row;
        if (gr < nrows) {
            *reinterpret_cast<uint4*>(&H[(size_t)gr * NC + cg * 8]) =
                *reinterpret_cast<const uint4*>(&Hl[row * SPH + cg * 8]);
        }
    }
}

__device__ __forceinline__ float2 u2f2(unsigned u) {
    __half2 h;
    *reinterpret_cast<unsigned*>(&h) = u;
    return __half22float2(h);
}

// out[n][f] = epilogue( dinv[n]*(H[n][f] + sum_{e in row n} H[ssrc[e]][f]) + b[f] )
// 32 threads per node, FPT = NC/32 features per thread, 8 nodes per block.
template <int NC, bool BN, bool HOUT>
__global__ __launch_bounds__(256) void agg_h(
    const __half* __restrict__ H, const int* __restrict__ row_ptr,
    const int* __restrict__ ssrc, const float* __restrict__ dinv,
    const float* __restrict__ b, const float* __restrict__ g,
    const float* __restrict__ be, const float* __restrict__ m,
    const float* __restrict__ v, void* __restrict__ out, int n) {
    constexpr int FPT = NC / 32;
    const int tid = threadIdx.x;
    const int node = blockIdx.x * 8 + (tid >> 5);
    const int lane = tid & 31;
    const int f0 = lane * FPT;
    if (node >= n) return;

    const int e0 = row_ptr[node];
    const int e1 = row_ptr[node + 1];

    if constexpr (FPT == 4) {
        uint2 su = *reinterpret_cast<const uint2*>(&H[(size_t)node * NC + f0]);
        float2 slo = u2f2(su.x), shi = u2f2(su.y);
        float4 A0 = {slo.x, slo.y, shi.x, shi.y};
        float4 A1 = {0, 0, 0, 0}, A2 = {0, 0, 0, 0}, A3 = {0, 0, 0, 0};
        int e = e0;
        for (; e + 3 < e1; e += 4) {
            const int sA = ssrc[e], sB = ssrc[e + 1], sC = ssrc[e + 2], sD = ssrc[e + 3];
            const uint2 uA = *reinterpret_cast<const uint2*>(&H[(size_t)sA * NC + f0]);
            const uint2 uB = *reinterpret_cast<const uint2*>(&H[(size_t)sB * NC + f0]);
            const uint2 uC = *reinterpret_cast<const uint2*>(&H[(size_t)sC * NC + f0]);
            const uint2 uD = *reinterpret_cast<const uint2*>(&H[(size_t)sD * NC + f0]);
            float2 l, h;
            l = u2f2(uA.x); h = u2f2(uA.y);
            A0.x += l.x; A0.y += l.y; A0.z += h.x; A0.w += h.y;
            l = u2f2(uB.x); h = u2f2(uB.y);
            A1.x += l.x; A1.y += l.y; A1.z += h.x; A1.w += h.y;
            l = u2f2(uC.x); h = u2f2(uC.y);
            A2.x += l.x; A2.y += l.y; A2.z += h.x; A2.w += h.y;
            l = u2f2(uD.x); h = u2f2(uD.y);
            A3.x += l.x; A3.y += l.y; A3.z += h.x; A3.w += h.y;
        }
        for (; e < e1; ++e) {
            const uint2 u = *reinterpret_cast<const uint2*>(&H[(size_t)ssrc[e] * NC + f0]);
            float2 l = u2f2(u.x), h = u2f2(u.y);
            A1.x += l.x; A1.y += l.y; A1.z += h.x; A1.w += h.y;
        }
        float4 acc;
        acc.x = (A0.x + A1.x) + (A2.x + A3.x);
        acc.y = (A0.y + A1.y) + (A2.y + A3.y);
        acc.z = (A0.z + A1.z) + (A2.z + A3.z);
        acc.w = (A0.w + A1.w) + (A2.w + A3.w);
        const float dn = dinv[node];
        float o[4] = {acc.x * dn + b[f0], acc.y * dn + b[f0 + 1],
                      acc.z * dn + b[f0 + 2], acc.w * dn + b[f0 + 3]};
        if constexpr (BN) {
#pragma unroll
            for (int j = 0; j < 4; ++j) {
                float val = (o[j] - m[f0 + j]) * rsqrtf(v[f0 + j] + BN_EPS) * g[f0 + j] + be[f0 + j];
                o[j] = val > 0.f ? val : LRELU_SLOPE * val;
            }
        }
        if constexpr (HOUT) {
            __half2 p0 = __floats2half2_rn(o[0], o[1]);
            __half2 p1 = __floats2half2_rn(o[2], o[3]);
            uint2 st;
            st.x = *reinterpret_cast<unsigned*>(&p0);
            st.y = *reinterpret_cast<unsigned*>(&p1);
            *reinterpret_cast<uint2*>(&((__half*)out)[(size_t)node * NC + f0]) = st;
        } else {
            float4 ov = {o[0], o[1], o[2], o[3]};
            *reinterpret_cast<float4*>(&((float*)out)[(size_t)node * NC + f0]) = ov;
        }
    } else {
        unsigned su = *reinterpret_cast<const unsigned*>(&H[(size_t)node * NC + f0]);
        float2 A0 = u2f2(su);
        float2 A1 = {0, 0}, A2 = {0, 0}, A3 = {0, 0};
        int e = e0;
        for (; e + 3 < e1; e += 4) {
            const int sA = ssrc[e], sB = ssrc[e + 1], sC = ssrc[e + 2], sD = ssrc[e + 3];
            const unsigned uA = *reinterpret_cast<const unsigned*>(&H[(size_t)sA * NC + f0]);
            const unsigned uB = *reinterpret_cast<const unsigned*>(&H[(size_t)sB * NC + f0]);
            const unsigned uC = *reinterpret_cast<const unsigned*>(&H[(size_t)sC * NC + f0]);
            const unsigned uD = *reinterpret_cast<const unsigned*>(&H[(size_t)sD * NC + f0]);
            float2 f;
            f = u2f2(uA); A0.x += f.x; A0.y += f.y;
            f = u2f2(uB); A1.x += f.x; A1.y += f.y;
            f = u2f2(uC); A2.x += f.x; A2.y += f.y;
            f = u2f2(uD); A3.x += f.x; A3.y += f.y;
        }
        for (; e < e1; ++e) {
            float2 f = u2f2(*reinterpret_cast<const unsigned*>(&H[(size_t)ssrc[e] * NC + f0]));
            A1.x += f.x; A1.y += f.y;
        }
        float2 acc;
        acc.x = (A0.x + A1.x) + (A2.x + A3.x);
        acc.y = (A0.y + A1.y) + (A2.y + A3.y);
        const float dn = dinv[node];
        float o0 = acc.x * dn + b[f0];
        float o1 = acc.y * dn + b[f0 + 1];
        if constexpr (BN) {
            o0 = (o0 - m[f0]) * rsqrtf(v[f0] + BN_EPS) * g[f0] + be[f0];
            o0 = o0 > 0.f ? o0 : LRELU_SLOPE * o0;
            o1 = (o1 - m[f0 + 1]) * rsqrtf(v[f0 + 1] + BN_EPS) * g[f0 + 1] + be[f0 + 1];
            o1 = o1 > 0.f ? o1 : LRELU_SLOPE * o1;
        }
        if constexpr (HOUT) {
            __half2 p0 = __floats2half2_rn(o0, o1);
            *reinterpret_cast<unsigned*>(&((__half*)out)[(size_t)node * NC + f0]) =
                *reinterpret_cast<unsigned*>(&p0);
        } else {
            float2 ov = {o0, o1};
            *reinterpret_cast<float2*>(&((float*)out)[(size_t)node * NC + f0]) = ov;
        }
    }
}

extern "C" void kernel_launch(void* const* d_in, const int* in_sizes, int n_in,
                              void* d_out, int out_size, void* d_ws, size_t ws_size,
                              hipStream_t stream) {
    const float* x  = (const float*)d_in[0];
    const int* ei   = (const int*)d_in[1];
    const float* W1 = (const float*)d_in[2];
    const float* b1 = (const float*)d_in[3];
    const float* g1 = (const float*)d_in[4];
    const float* be1= (const float*)d_in[5];
    const float* m1 = (const float*)d_in[6];
    const float* v1 = (const float*)d_in[7];
    const float* W2 = (const float*)d_in[8];
    const float* b2 = (const float*)d_in[9];
    const float* g2 = (const float*)d_in[10];
    const float* be2= (const float*)d_in[11];
    const float* m2 = (const float*)d_in[12];
    const float* v2 = (const float*)d_in[13];
    const float* W3 = (const float*)d_in[14];
    const float* b3 = (const float*)d_in[15];
    float* out = (float*)d_out;

    const int N = in_sizes[0] / 128;
    const int E = in_sizes[1] / 2;
    const int* srcIdx = ei;       // edge_index[0]
    const int* dstIdx = ei + E;   // edge_index[1]

    char* p = (char*)d_ws;
    auto carve = [&](size_t bytes) -> void* {
        void* r = (void*)p;
        p += (bytes + 255) & ~(size_t)255;
        return r;
    };
    int* cnt       = (int*)carve((size_t)N * 4);
    int* incl      = (int*)carve((size_t)N * 4);
    int* part      = (int*)carve(1024);
    int* poff      = (int*)carve(1024);
    int* row_ptr   = (int*)carve((size_t)(N + 1) * 4);
    int* cursor    = (int*)carve((size_t)N * 4);
    float* dinv    = (float*)carve((size_t)N * 4);
    int* ssrc      = (int*)carve((size_t)E * 4);
    __half* Hb     = (__half*)carve((size_t)N * 128 * 2);
    __half* Xb     = (__half*)carve((size_t)N * 128 * 2);
    _Float16* W1t  = (_Float16*)carve(128 * 136 * 2);
    _Float16* W2t  = (_Float16*)carve(128 * 136 * 2);
    _Float16* W3t  = (_Float16*)carve(64 * 136 * 2);
    (void)ws_size; (void)n_in; (void)out_size;

    const int nb_n = (N + 255) / 256;  // 196 (fits single-block scan2)
    const int nb_e = (E + 255) / 256;

    prep_w<<<160, 256, 0, stream>>>(W1, W2, W3, W1t, W2t, W3t);
    zero_i32<<<nb_n, 256, 0, stream>>>(cnt, N);
    hist_kernel<<<nb_e, 256, 0, stream>>>(dstIdx, cnt, E);
    scan1<<<nb_n, 256, 0, stream>>>(cnt, incl, part, N);
    scan2<<<1, 256, 0, stream>>>(part, poff, nb_n);
    scan3<<<nb_n, 256, 0, stream>>>(cnt, incl, poff, row_ptr, cursor, dinv, N, E);
    scatter_kernel<<<nb_e, 256, 0, stream>>>(srcIdx, dstIdx, cursor, ssrc, E);

    const int gb = (N + 63) / 64;
    const int ab = (N + 7) / 8;

    // Layer 1: x (f32) -> Hb -> Xb (fp16)
    gemm_mfma<128, true><<<gb, 256, 0, stream>>>(x, W1t, dinv, Hb, N);
    agg_h<128, true, true><<<ab, 256, 0, stream>>>(
        Hb, row_ptr, ssrc, dinv, b1, g1, be1, m1, v1, Xb, N);

    // Layer 2: Xb (fp16) -> Hb -> Xb (fp16)
    gemm_mfma<128, false><<<gb, 256, 0, stream>>>(Xb, W2t, dinv, Hb, N);
    agg_h<128, true, true><<<ab, 256, 0, stream>>>(
        Hb, row_ptr, ssrc, dinv, b2, g2, be2, m2, v2, Xb, N);

    // Layer 3: Xb (fp16) -> Hb (64 cols) -> out (f32)
    gemm_mfma<64, false><<<gb, 256, 0, stream>>>(Xb, W3t, dinv, Hb, N);
    agg_h<64, false, false><<<ab, 256, 0, stream>>>(
        Hb, row_ptr, ssrc, dinv, b3, nullptr, nullptr, nullptr, nullptr, out, N);
}

// Round 7
// 266.148 us; speedup vs baseline: 1.8010x; 1.1678x over previous
//
#include <hip/hip_runtime.h>
#include <hip/hip_fp16.h>

// GCN 3-layer fused pipeline for MI355X.
// Bucketed CSR build (bin -> bucket-hist -> scan -> local scatter), then per
// layer: fp16 MFMA GEMM (W in LDS, dinv-scaled fp16 H epilogue) -> pull-mode
// aggregation over fp16 H with fused bias/BN/LeakyReLU epilogue.

#define LRELU_SLOPE 0.1f
#define BN_EPS 1e-5f
#define BCAP 20480   // max edges per 1024-node bucket (mean 16384, 32 sigma)

typedef _Float16 half8 __attribute__((ext_vector_type(8)));
typedef float f32x4 __attribute__((ext_vector_type(4)));

__global__ void init_bcur(int* __restrict__ bcur) {
    int i = threadIdx.x;
    if (i < 64) bcur[i] = i * BCAP;
}

// Phase A: bin edges into per-bucket regions as packed (src<<32|dst) pairs.
// Block stages its edge chunk in LDS, histograms buckets, reserves global
// ranges (one atomic per bucket per block), then appends.
__global__ __launch_bounds__(256) void bin_pass(const int* __restrict__ src,
                                                const int* __restrict__ dst, int E,
                                                int* __restrict__ bcur,
                                                unsigned long long* __restrict__ pairs) {
    __shared__ int sd[3200], ss[3200];
    __shared__ int lcur[64];
    const int tid = threadIdx.x;
    const int chunk = (E + gridDim.x - 1) / gridDim.x;  // 3125 at E=800k
    const int e0 = blockIdx.x * chunk;
    const int ecnt = min(chunk, E - e0);
    for (int j = tid; j < ecnt; j += 256) {
        sd[j] = dst[e0 + j];
        ss[j] = src[e0 + j];
    }
    if (tid < 64) lcur[tid] = 0;
    __syncthreads();
    for (int j = tid; j < ecnt; j += 256) atomicAdd(&lcur[sd[j] >> 10], 1);
    __syncthreads();
    if (tid < 64) lcur[tid] = atomicAdd(&bcur[tid], lcur[tid]);  // base into lcur
    __syncthreads();
    for (int j = tid; j < ecnt; j += 256) {
        const int b = sd[j] >> 10;
        const int pos = atomicAdd(&lcur[b], 1);
        pairs[pos] = ((unsigned long long)(unsigned)ss[j] << 32) | (unsigned)sd[j];
    }
}

// Per-bucket degree histogram (LDS, no global atomics) -> dense cnt write.
__global__ __launch_bounds__(512) void hist_bucket(const unsigned long long* __restrict__ pairs,
                                                   const int* __restrict__ bcur,
                                                   int* __restrict__ cnt, int N) {
    __shared__ int h[1024];
    const int b = blockIdx.x;
    const int base = b << 10;
    const int nn = min(1024, N - base);
    const int cntb = bcur[b] - b * BCAP;
    for (int i = threadIdx.x; i < 1024; i += 512) h[i] = 0;
    __syncthreads();
    const unsigned long long* pb = pairs + (size_t)b * BCAP;
    for (int j = threadIdx.x; j < cntb; j += 512) {
        const int d = (int)(pb[j] & 0xffffffffull);
        atomicAdd(&h[d - base], 1);
    }
    __syncthreads();
    for (int i = threadIdx.x; i < nn; i += 512) cnt[base + i] = h[i];
}

// Block-level inclusive scan (256 elements per block) + per-block totals.
__global__ void scan1(const int* __restrict__ cnt, int* __restrict__ incl,
                      int* __restrict__ part, int n) {
    __shared__ int s[256];
    int tid = threadIdx.x;
    int gid = blockIdx.x * 256 + tid;
    int v = (gid < n) ? cnt[gid] : 0;
    s[tid] = v;
    __syncthreads();
    for (int off = 1; off < 256; off <<= 1) {
        int t = (tid >= off) ? s[tid - off] : 0;
        __syncthreads();
        s[tid] += t;
        __syncthreads();
    }
    if (gid < n) incl[gid] = s[tid];
    if (tid == 255) part[blockIdx.x] = s[255];
}

__global__ void scan2(const int* __restrict__ part, int* __restrict__ poff, int nb) {
    __shared__ int s[256];
    int tid = threadIdx.x;
    int v = (tid < nb) ? part[tid] : 0;
    s[tid] = v;
    __syncthreads();
    for (int off = 1; off < 256; off <<= 1) {
        int t = (tid >= off) ? s[tid - off] : 0;
        __syncthreads();
        s[tid] += t;
        __syncthreads();
    }
    poff[tid] = s[tid] - v;  // exclusive
}

__global__ void scan3(const int* __restrict__ cnt, const int* __restrict__ incl,
                      const int* __restrict__ poff, int* __restrict__ row_ptr,
                      float* __restrict__ dinv, int n, int E) {
    int gid = blockIdx.x * 256 + threadIdx.x;
    if (gid < n) {
        int c = cnt[gid];
        row_ptr[gid] = incl[gid] - c + poff[blockIdx.x];
        dinv[gid] = rsqrtf(1.0f + (float)c);
    }
    if (gid == 0) row_ptr[n] = E;
}

// Phase B: per-bucket local CSR scatter with LDS cursors; stores land in a
// ~65KB window owned by one block (single-XCD L2 locality).
__global__ __launch_bounds__(512) void build_csr(const unsigned long long* __restrict__ pairs,
                                                 const int* __restrict__ bcur,
                                                 const int* __restrict__ row_ptr,
                                                 int* __restrict__ ssrc_g, int N) {
    __shared__ int cur[1024];
    const int b = blockIdx.x;
    const int base = b << 10;
    const int nn = min(1024, N - base);
    const int cntb = bcur[b] - b * BCAP;
    for (int i = threadIdx.x; i < nn; i += 512) cur[i] = row_ptr[base + i];
    __syncthreads();
    const unsigned long long* pb = pairs + (size_t)b * BCAP;
    for (int j = threadIdx.x; j < cntb; j += 512) {
        const unsigned long long p = pb[j];
        const int d = (int)(p & 0xffffffffull);
        const int s = (int)(p >> 32);
        const int pos = atomicAdd(&cur[d - base], 1);
        ssrc_g[pos] = s;
    }
}

// Convert + transpose all three W matrices to padded fp16 Wt[c][k] (stride 136).
__global__ void prep_w(const float* __restrict__ W1, const float* __restrict__ W2,
                       const float* __restrict__ W3, _Float16* __restrict__ W1t,
                       _Float16* __restrict__ W2t, _Float16* __restrict__ W3t) {
    int i = blockIdx.x * 256 + threadIdx.x;
    if (i < 16384) {
        int k = i >> 7, c = i & 127;
        W1t[c * 136 + k] = (_Float16)W1[i];
    } else if (i < 32768) {
        int j = i - 16384;
        int k = j >> 7, c = j & 127;
        W2t[c * 136 + k] = (_Float16)W2[j];
    } else if (i < 40960) {
        int j = i - 32768;
        int k = j >> 6, c = j & 63;
        W3t[c * 136 + k] = (_Float16)W3[j];
    }
}

// H[r][c] = fp16( (sum_k A[r][k] * W[k][c]) * dinv[r] ),  K fixed at 128.
template <int NC, bool AF32>
__global__ __launch_bounds__(256) void gemm_mfma(const void* __restrict__ Ain,
                                                 const _Float16* __restrict__ Wt,
                                                 const float* __restrict__ dinv,
                                                 __half* __restrict__ H, int nrows) {
    constexpr int NT = NC / 16;                    // N fragments per wave
    constexpr int SPH = (NC == 128) ? 136 : 88;    // Hl padded row (halves)
    __shared__ _Float16 smem[NC * 136];

    const int tid = threadIdx.x;
    const int row0 = blockIdx.x * 64;

    {
        const uint4* src = reinterpret_cast<const uint4*>(Wt);
        uint4* dst = reinterpret_cast<uint4*>(smem);
        for (int i = tid; i < NC * 17; i += 256) dst[i] = src[i];
    }
    __syncthreads();

    const int w = tid >> 6;
    const int lane = tid & 63;
    const int l15 = lane & 15;
    const int kg = lane >> 4;  // 0..3

    int ar = row0 + w * 16 + l15;
    if (ar > nrows - 1) ar = nrows - 1;
    half8 a[4];
#pragma unroll
    for (int ks = 0; ks < 4; ++ks) {
        const int cb = ks * 32 + kg * 8;
        if constexpr (AF32) {
            const float* Xf = (const float*)Ain;
            const float4 x0 = *reinterpret_cast<const float4*>(&Xf[(size_t)ar * 128 + cb]);
            const float4 x1 = *reinterpret_cast<const float4*>(&Xf[(size_t)ar * 128 + cb + 4]);
            half8 av;
            av[0] = (_Float16)x0.x; av[1] = (_Float16)x0.y;
            av[2] = (_Float16)x0.z; av[3] = (_Float16)x0.w;
            av[4] = (_Float16)x1.x; av[5] = (_Float16)x1.y;
            av[6] = (_Float16)x1.z; av[7] = (_Float16)x1.w;
            a[ks] = av;
        } else {
            const __half* Xh = (const __half*)Ain;
            a[ks] = *reinterpret_cast<const half8*>(&Xh[(size_t)ar * 128 + cb]);
        }
    }

    f32x4 acc[NT];
#pragma unroll
    for (int nt = 0; nt < NT; ++nt) acc[nt] = {0.f, 0.f, 0.f, 0.f};

#pragma unroll
    for (int nt = 0; nt < NT; ++nt) {
        const int c = nt * 16 + l15;
#pragma unroll
        for (int ks = 0; ks < 4; ++ks) {
            const half8 b = *reinterpret_cast<const half8*>(&smem[c * 136 + ks * 32 + kg * 8]);
            acc[nt] = __builtin_amdgcn_mfma_f32_16x16x32_f16(a[ks], b, acc[nt], 0, 0, 0);
        }
    }

    __syncthreads();  // all B-reads done; reuse smem as Hl[64][SPH]

    float dv[4];
#pragma unroll
    for (int r = 0; r < 4; ++r) {
        int gr = row0 + w * 16 + kg * 4 + r;
        if (gr > nrows - 1) gr = nrows - 1;
        dv[r] = dinv[gr];
    }
    _Float16* Hl = smem;
#pragma unroll
    for (int nt = 0; nt < NT; ++nt) {
#pragma unroll
        for (int r = 0; r < 4; ++r) {
            Hl[(w * 16 + kg * 4 + r) * SPH + nt * 16 + l15] = (_Float16)(acc[nt][r] * dv[r]);
        }
    }
    __syncthreads();

    constexpr int CG = NC / 8;
    for (int i = tid; i < 64 * CG; i += 256) {
        const int row = i / CG, cg = i % CG;
        const int gr = row0 + row;
        if (gr < nrows) {
            *reinterpret_cast<uint4*>(&H[(size_t)gr * NC + cg * 8]) =
                *reinterpret_cast<const uint4*>(&Hl[row * SPH + cg * 8]);
        }
    }
}

__device__ __forceinline__ float2 u2f2(unsigned u) {
    __half2 h;
    *reinterpret_cast<unsigned*>(&h) = u;
    return __half22float2(h);
}

// out[n][f] = epilogue( dinv[n]*(H[n][f] + sum_{e in row n} H[ssrc[e]][f]) + b[f] )
template <int NC, bool BN, bool HOUT>
__global__ __launch_bounds__(256) void agg_h(
    const __half* __restrict__ H, const int* __restrict__ row_ptr,
    const int* __restrict__ ssrc, const float* __restrict__ dinv,
    const float* __restrict__ b, const float* __restrict__ g,
    const float* __restrict__ be, const float* __restrict__ m,
    const float* __restrict__ v, void* __restrict__ out, int n) {
    constexpr int FPT = NC / 32;
    const int tid = threadIdx.x;
    const int node = blockIdx.x * 8 + (tid >> 5);
    const int lane = tid & 31;
    const int f0 = lane * FPT;
    if (node >= n) return;

    const int e0 = row_ptr[node];
    const int e1 = row_ptr[node + 1];

    if constexpr (FPT == 4) {
        uint2 su = *reinterpret_cast<const uint2*>(&H[(size_t)node * NC + f0]);
        float2 slo = u2f2(su.x), shi = u2f2(su.y);
        float4 A0 = {slo.x, slo.y, shi.x, shi.y};
        float4 A1 = {0, 0, 0, 0}, A2 = {0, 0, 0, 0}, A3 = {0, 0, 0, 0};
        int e = e0;
        for (; e + 3 < e1; e += 4) {
            const int sA = ssrc[e], sB = ssrc[e + 1], sC = ssrc[e + 2], sD = ssrc[e + 3];
            const uint2 uA = *reinterpret_cast<const uint2*>(&H[(size_t)sA * NC + f0]);
            const uint2 uB = *reinterpret_cast<const uint2*>(&H[(size_t)sB * NC + f0]);
            const uint2 uC = *reinterpret_cast<const uint2*>(&H[(size_t)sC * NC + f0]);
            const uint2 uD = *reinterpret_cast<const uint2*>(&H[(size_t)sD * NC + f0]);
            float2 l, h;
            l = u2f2(uA.x); h = u2f2(uA.y);
            A0.x += l.x; A0.y += l.y; A0.z += h.x; A0.w += h.y;
            l = u2f2(uB.x); h = u2f2(uB.y);
            A1.x += l.x; A1.y += l.y; A1.z += h.x; A1.w += h.y;
            l = u2f2(uC.x); h = u2f2(uC.y);
            A2.x += l.x; A2.y += l.y; A2.z += h.x; A2.w += h.y;
            l = u2f2(uD.x); h = u2f2(uD.y);
            A3.x += l.x; A3.y += l.y; A3.z += h.x; A3.w += h.y;
        }
        for (; e < e1; ++e) {
            const uint2 u = *reinterpret_cast<const uint2*>(&H[(size_t)ssrc[e] * NC + f0]);
            float2 l = u2f2(u.x), h = u2f2(u.y);
            A1.x += l.x; A1.y += l.y; A1.z += h.x; A1.w += h.y;
        }
        float4 acc;
        acc.x = (A0.x + A1.x) + (A2.x + A3.x);
        acc.y = (A0.y + A1.y) + (A2.y + A3.y);
        acc.z = (A0.z + A1.z) + (A2.z + A3.z);
        acc.w = (A0.w + A1.w) + (A2.w + A3.w);
        const float dn = dinv[node];
        float o[4] = {acc.x * dn + b[f0], acc.y * dn + b[f0 + 1],
                      acc.z * dn + b[f0 + 2], acc.w * dn + b[f0 + 3]};
        if constexpr (BN) {
#pragma unroll
            for (int j = 0; j < 4; ++j) {
                float val = (o[j] - m[f0 + j]) * rsqrtf(v[f0 + j] + BN_EPS) * g[f0 + j] + be[f0 + j];
                o[j] = val > 0.f ? val : LRELU_SLOPE * val;
            }
        }
        if constexpr (HOUT) {
            __half2 p0 = __floats2half2_rn(o[0], o[1]);
            __half2 p1 = __floats2half2_rn(o[2], o[3]);
            uint2 st;
            st.x = *reinterpret_cast<unsigned*>(&p0);
            st.y = *reinterpret_cast<unsigned*>(&p1);
            *reinterpret_cast<uint2*>(&((__half*)out)[(size_t)node * NC + f0]) = st;
        } else {
            float4 ov = {o[0], o[1], o[2], o[3]};
            *reinterpret_cast<float4*>(&((float*)out)[(size_t)node * NC + f0]) = ov;
        }
    } else {
        unsigned su = *reinterpret_cast<const unsigned*>(&H[(size_t)node * NC + f0]);
        float2 A0 = u2f2(su);
        float2 A1 = {0, 0}, A2 = {0, 0}, A3 = {0, 0};
        int e = e0;
        for (; e + 3 < e1; e += 4) {
            const int sA = ssrc[e], sB = ssrc[e + 1], sC = ssrc[e + 2], sD = ssrc[e + 3];
            const unsigned uA = *reinterpret_cast<const unsigned*>(&H[(size_t)sA * NC + f0]);
            const unsigned uB = *reinterpret_cast<const unsigned*>(&H[(size_t)sB * NC + f0]);
            const unsigned uC = *reinterpret_cast<const unsigned*>(&H[(size_t)sC * NC + f0]);
            const unsigned uD = *reinterpret_cast<const unsigned*>(&H[(size_t)sD * NC + f0]);
            float2 f;
            f = u2f2(uA); A0.x += f.x; A0.y += f.y;
            f = u2f2(uB); A1.x += f.x; A1.y += f.y;
            f = u2f2(uC); A2.x += f.x; A2.y += f.y;
            f = u2f2(uD); A3.x += f.x; A3.y += f.y;
        }
        for (; e < e1; ++e) {
            float2 f = u2f2(*reinterpret_cast<const unsigned*>(&H[(size_t)ssrc[e] * NC + f0]));
            A1.x += f.x; A1.y += f.y;
        }
        float2 acc;
        acc.x = (A0.x + A1.x) + (A2.x + A3.x);
        acc.y = (A0.y + A1.y) + (A2.y + A3.y);
        const float dn = dinv[node];
        float o0 = acc.x * dn + b[f0];
        float o1 = acc.y * dn + b[f0 + 1];
        if constexpr (BN) {
            o0 = (o0 - m[f0]) * rsqrtf(v[f0] + BN_EPS) * g[f0] + be[f0];
            o0 = o0 > 0.f ? o0 : LRELU_SLOPE * o0;
            o1 = (o1 - m[f0 + 1]) * rsqrtf(v[f0 + 1] + BN_EPS) * g[f0 + 1] + be[f0 + 1];
            o1 = o1 > 0.f ? o1 : LRELU_SLOPE * o1;
        }
        if constexpr (HOUT) {
            __half2 p0 = __floats2half2_rn(o0, o1);
            *reinterpret_cast<unsigned*>(&((__half*)out)[(size_t)node * NC + f0]) =
                *reinterpret_cast<unsigned*>(&p0);
        } else {
            float2 ov = {o0, o1};
            *reinterpret_cast<float2*>(&((float*)out)[(size_t)node * NC + f0]) = ov;
        }
    }
}

extern "C" void kernel_launch(void* const* d_in, const int* in_sizes, int n_in,
                              void* d_out, int out_size, void* d_ws, size_t ws_size,
                              hipStream_t stream) {
    const float* x  = (const float*)d_in[0];
    const int* ei   = (const int*)d_in[1];
    const float* W1 = (const float*)d_in[2];
    const float* b1 = (const float*)d_in[3];
    const float* g1 = (const float*)d_in[4];
    const float* be1= (const float*)d_in[5];
    const float* m1 = (const float*)d_in[6];
    const float* v1 = (const float*)d_in[7];
    const float* W2 = (const float*)d_in[8];
    const float* b2 = (const float*)d_in[9];
    const float* g2 = (const float*)d_in[10];
    const float* be2= (const float*)d_in[11];
    const float* m2 = (const float*)d_in[12];
    const float* v2 = (const float*)d_in[13];
    const float* W3 = (const float*)d_in[14];
    const float* b3 = (const float*)d_in[15];
    float* out = (float*)d_out;

    const int N = in_sizes[0] / 128;
    const int E = in_sizes[1] / 2;
    const int* srcIdx = ei;       // edge_index[0]
    const int* dstIdx = ei + E;   // edge_index[1]
    const int nbuck = (N + 1023) >> 10;  // 49

    char* p = (char*)d_ws;
    auto carve = [&](size_t bytes) -> void* {
        void* r = (void*)p;
        p += (bytes + 255) & ~(size_t)255;
        return r;
    };
    int* cnt       = (int*)carve((size_t)N * 4);
    int* incl      = (int*)carve((size_t)N * 4);
    int* part      = (int*)carve(1024);
    int* poff      = (int*)carve(1024);
    int* row_ptr   = (int*)carve((size_t)(N + 1) * 4);
    int* bcur      = (int*)carve(64 * 4);
    float* dinv    = (float*)carve((size_t)N * 4);
    int* ssrc      = (int*)carve((size_t)E * 4);
    unsigned long long* pairs = (unsigned long long*)carve((size_t)nbuck * BCAP * 8);
    __half* Hb     = (__half*)carve((size_t)N * 128 * 2);
    __half* Xb     = (__half*)carve((size_t)N * 128 * 2);
    _Float16* W1t  = (_Float16*)carve(128 * 136 * 2);
    _Float16* W2t  = (_Float16*)carve(128 * 136 * 2);
    _Float16* W3t  = (_Float16*)carve(64 * 136 * 2);
    (void)ws_size; (void)n_in; (void)out_size;

    const int nb_n = (N + 255) / 256;  // 196 (fits single-block scan2)

    prep_w<<<160, 256, 0, stream>>>(W1, W2, W3, W1t, W2t, W3t);
    init_bcur<<<1, 64, 0, stream>>>(bcur);
    bin_pass<<<256, 256, 0, stream>>>(srcIdx, dstIdx, E, bcur, pairs);
    hist_bucket<<<nbuck, 512, 0, stream>>>(pairs, bcur, cnt, N);
    scan1<<<nb_n, 256, 0, stream>>>(cnt, incl, part, N);
    scan2<<<1, 256, 0, stream>>>(part, poff, nb_n);
    scan3<<<nb_n, 256, 0, stream>>>(cnt, incl, poff, row_ptr, dinv, N, E);
    build_csr<<<nbuck, 512, 0, stream>>>(pairs, bcur, row_ptr, ssrc, N);

    const int gb = (N + 63) / 64;
    const int ab = (N + 7) / 8;

    // Layer 1: x (f32) -> Hb -> Xb (fp16)
    gemm_mfma<128, true><<<gb, 256, 0, stream>>>(x, W1t, dinv, Hb, N);
    agg_h<128, true, true><<<ab, 256, 0, stream>>>(
        Hb, row_ptr, ssrc, dinv, b1, g1, be1, m1, v1, Xb, N);

    // Layer 2: Xb (fp16) -> Hb -> Xb (fp16)
    gemm_mfma<128, false><<<gb, 256, 0, stream>>>(Xb, W2t, dinv, Hb, N);
    agg_h<128, true, true><<<ab, 256, 0, stream>>>(
        Hb, row_ptr, ssrc, dinv, b2, g2, be2, m2, v2, Xb, N);

    // Layer 3: Xb (fp16) -> Hb (64 cols) -> out (f32)
    gemm_mfma<64, false><<<gb, 256, 0, stream>>>(Xb, W3t, dinv, Hb, N);
    agg_h<64, false, false><<<ab, 256, 0, stream>>>(
        Hb, row_ptr, ssrc, dinv, b3, nullptr, nullptr, nullptr, nullptr, out, N);
}